// Round 8
// baseline (604.701 us; speedup 1.0000x reference)
//
#include <hip/hip_runtime.h>

#define NT 8192       // tokens
#define NJ 24         // joints
#define DD 256        // per-joint dim
#define NH 8          // heads
#define FF 32         // head dim
#define C3 768        // q(256) + k(256) + v(256)

typedef __attribute__((ext_vector_type(8))) _Float16 f16x8;
typedef __attribute__((ext_vector_type(2))) _Float16 half2v;
typedef __attribute__((ext_vector_type(4))) float f32x4;

__device__ __forceinline__ unsigned short f2h(float f) {
    union { _Float16 h; unsigned short u; } c;
    c.h = (_Float16)f;
    return c.u;
}

// fused dot2: a,b are packed f16 pairs (as uint), f32 accumulate
__device__ __forceinline__ float dot2(unsigned int a, unsigned int b, float c) {
#if __has_builtin(__builtin_amdgcn_fdot2)
    return __builtin_amdgcn_fdot2(__builtin_bit_cast(half2v, a),
                                  __builtin_bit_cast(half2v, b), c, false);
#else
    half2v ha = __builtin_bit_cast(half2v, a);
    half2v hb = __builtin_bit_cast(half2v, b);
    return c + (float)ha[0] * (float)hb[0] + (float)ha[1] * (float)hb[1];
#endif
}

// async global->LDS, 16B per lane. LDS dest = base + lane*16 (wave-uniform base).
__device__ __forceinline__ void gload16(const void* g, void* l) {
    __builtin_amdgcn_global_load_lds(
        (const __attribute__((address_space(1))) unsigned int*)g,
        (__attribute__((address_space(3))) unsigned int*)l, 16, 0, 0);
}

// ---------------- pack kernel (coalesced LDS-transpose) ----------------
__global__ __launch_bounds__(256)
void pack_wb(const float* __restrict__ Wq, const float* __restrict__ Wk,
             const float* __restrict__ Wv, unsigned short* __restrict__ wbt,
             const float* __restrict__ bq, const float* __restrict__ bk,
             const float* __restrict__ bv, float* __restrict__ bias) {
    const int b = blockIdx.x;
    const int tid = threadIdx.x;

    if (b < 208) {
        const float* src;
        int n0, nrep, crow0;
        if (b < 192) {
            int h = b / 24, n = b % 24;
            src = Wq + (size_t)(h * NJ + n) * (DD * FF);
            n0 = n; nrep = 1; crow0 = h * FF;
        } else if (b < 200) {
            int h = b - 192;
            src = Wk + (size_t)h * (DD * FF);
            n0 = 0; nrep = NJ; crow0 = 256 + h * FF;
        } else {
            int h = b - 200;
            src = Wv + (size_t)h * (DD * FF);
            n0 = 0; nrep = NJ; crow0 = 512 + h * FF;
        }
        __shared__ unsigned short T[32][264];   // +8 pad
        #pragma unroll
        for (int it = 0; it < 4; ++it) {
            int e = (it * 256 + tid) * 8;   // multiple of 8
            int d = e >> 5;
            int f = e & 31;
            float4 v0 = *(const float4*)(src + e);
            float4 v1 = *(const float4*)(src + e + 4);
            T[f + 0][d] = f2h(v0.x); T[f + 1][d] = f2h(v0.y);
            T[f + 2][d] = f2h(v0.z); T[f + 3][d] = f2h(v0.w);
            T[f + 4][d] = f2h(v1.x); T[f + 5][d] = f2h(v1.y);
            T[f + 6][d] = f2h(v1.z); T[f + 7][d] = f2h(v1.w);
        }
        __syncthreads();
        for (int rep = 0; rep < nrep; ++rep) {
            int n = n0 + rep;
            unsigned short* dst = wbt + ((size_t)n * C3 + crow0) * DD;
            #pragma unroll
            for (int it = 0; it < 4; ++it) {
                int q = it * 256 + tid;       // 0..1023
                int r = q >> 5;               // row 0..31
                int c8 = (q & 31) * 8;        // 8 shorts
                *(int4*)(dst + r * DD + c8) = *(const int4*)&T[r][c8];
            }
        }
    } else {
        int idx = (b - 208) * 256 + tid;
        int cb = idx % C3;
        int nb2 = idx / C3;
        float bvv;
        if (cb < 256) {
            int h = cb >> 5, f = cb & 31;
            bvv = bq[((h * NJ + nb2) * FF) + f];
        } else if (cb < 512) {
            int cc = cb - 256; int h = cc >> 5, f = cc & 31;
            bvv = bk[h * FF + f];
        } else {
            int cc = cb - 512; int h = cc >> 5, f = cc & 31;
            bvv = bv[h * FF + f];
        }
        bias[idx] = bvv;
    }
}

// ---------------- QKV projection GEMM ----------------
// 2-phase double-buffered pipeline (T3 minimum recipe):
//   per kb: {cvt+ds_write A(kb)} {issue B(kb+1)+A(kb+1)} {lgkm(0)+raw barrier}
//           {32 MFMA} {raw barrier}.
// Raw barriers (no vmcnt drain) keep next-tile loads in flight across the MFMA
// phase. B(kb) completion is implied by the compiler's vmcnt wait on pa(kb)
// (pa was issued AFTER B(kb) -> oldest-first vmcnt semantics cover B).
#define BM 128
#define BN 128

__global__ __launch_bounds__(256, 2)
void gemm_qkv(const float* __restrict__ x, const unsigned short* __restrict__ wbt,
              const float* __restrict__ bias, unsigned short* __restrict__ qkv,
              int t0, int mbs) {
    // XCD-chunked bijective swizzle: nwg = 144*mbs, always % 8 == 0.
    const int nwg = gridDim.x;
    const int cpx = nwg >> 3;
    const int bid = blockIdx.x;
    const int swz = (bid & 7) * cpx + (bid >> 3);
    const int nb = swz % 6;          // col block (0..5) — fastest: shares A-tile
    const int rest = swz / 6;
    const int mb = rest % mbs;       // token block
    const int nj = rest / mbs;       // joint

    const int tid = threadIdx.x;
    const int wave = tid >> 6, lane = tid & 63;

    __shared__ unsigned short As[2][BM * 64];   // 2 x 16 KB
    __shared__ unsigned short Bs[2][BN * 64];   // 2 x 16 KB

    f32x4 acc[4][4];
    #pragma unroll
    for (int i = 0; i < 4; ++i)
        #pragma unroll
        for (int j = 0; j < 4; ++j)
            #pragma unroll
            for (int r = 0; r < 4; ++r) acc[i][j][r] = 0.f;

    const int trow0 = t0 + mb * BM;
    const float* srcA = x + (size_t)trow0 * (NJ * DD) + nj * DD;
    const char* srcB = (const char*)(wbt + ((size_t)nj * C3 + (size_t)nb * BN) * DD);

    const int rg = lane >> 3;            // row within 8-row group (0..7)
    const int sc = (lane & 7) ^ rg;      // pre-swizzled source 16B-column (B staging)

    const int wr = (wave >> 1) * 64;
    const int wc = (wave & 1) * 64;
    const int lr = lane & 15;
    const int g  = lane >> 4;            // 0..3

    const float* aptr[4];
    #pragma unroll
    for (int it = 0; it < 4; ++it) {
        int q = it * 256 + tid;          // 0..1023
        int row = q >> 3;
        int c16 = q & 7;
        aptr[it] = srcA + (size_t)row * (NJ * DD) + c16 * 8;
    }

    // prologue: B(0) -> Bs[0] (issued FIRST), then A(0) -> pa regs
    #pragma unroll
    for (int i = 0; i < 4; ++i) {
        int row0 = wave * 32 + i * 8;
        gload16(srcB + (size_t)(row0 + rg) * (DD * 2) + sc * 16,
                (char*)Bs[0] + row0 * 128);
    }
    float4 pa[4][2];
    #pragma unroll
    for (int it = 0; it < 4; ++it) {
        pa[it][0] = *(const float4*)(aptr[it]);
        pa[it][1] = *(const float4*)(aptr[it] + 4);
    }

    #pragma unroll
    for (int kb = 0; kb < 4; ++kb) {
        const int cur = kb & 1;
        // 1. cvt + swizzled ds_write A(kb) into As[cur].
        //    Compiler inserts vmcnt wait for pa -> implies B(kb) (older) complete.
        #pragma unroll
        for (int it = 0; it < 4; ++it) {
            int q = it * 256 + tid;
            int row = q >> 3;
            int c16 = q & 7;
            float4 v0 = pa[it][0];
            float4 v1 = pa[it][1];
            f16x8 hv;
            hv[0] = (_Float16)v0.x; hv[1] = (_Float16)v0.y;
            hv[2] = (_Float16)v0.z; hv[3] = (_Float16)v0.w;
            hv[4] = (_Float16)v1.x; hv[5] = (_Float16)v1.y;
            hv[6] = (_Float16)v1.z; hv[7] = (_Float16)v1.w;
            int c16s = c16 ^ (row & 7);
            *(f16x8*)((char*)As[cur] + row * 128 + c16s * 16) = hv;
        }
        // 2. stage next tile (flies across the barrier + MFMA phase).
        //    Bs[cur^1] was last read by MFMA(kb-1); barrier#2 of iter kb-1 seals it.
        if (kb < 3) {
            #pragma unroll
            for (int i = 0; i < 4; ++i) {
                int row0 = wave * 32 + i * 8;
                gload16(srcB + (size_t)(row0 + rg) * (DD * 2) + (kb + 1) * 128 + sc * 16,
                        (char*)Bs[cur ^ 1] + row0 * 128);
            }
            #pragma unroll
            for (int it = 0; it < 4; ++it) {
                const float* p = aptr[it] + (kb + 1) * 64;
                pa[it][0] = *(const float4*)p;
                pa[it][1] = *(const float4*)(p + 4);
            }
        }
        // 3. LDS-write fence + raw barrier (NO vmcnt drain -> staged loads stay in flight)
        asm volatile("s_waitcnt lgkmcnt(0)" ::: "memory");
        __builtin_amdgcn_sched_barrier(0);
        __builtin_amdgcn_s_barrier();
        // 4. MFMA on As[cur]/Bs[cur]
        #pragma unroll
        for (int kk = 0; kk < 2; ++kk) {
            f16x8 a[4], b[4];
            #pragma unroll
            for (int i = 0; i < 4; ++i) {
                int row = wr + i * 16 + lr;
                int c16 = (kk * 4 + g) ^ (row & 7);
                a[i] = *(const f16x8*)((const char*)As[cur] + row * 128 + c16 * 16);
            }
            #pragma unroll
            for (int j = 0; j < 4; ++j) {
                int row = wc + j * 16 + lr;
                int c16 = (kk * 4 + g) ^ (row & 7);
                b[j] = *(const f16x8*)((const char*)Bs[cur] + row * 128 + c16 * 16);
            }
            #pragma unroll
            for (int i = 0; i < 4; ++i)
                #pragma unroll
                for (int j = 0; j < 4; ++j)
                    acc[i][j] = __builtin_amdgcn_mfma_f32_16x16x32_f16(a[i], b[j], acc[i][j], 0, 0, 0);
        }
        // 5. raw barrier: all MFMA(kb) reads done before next iter re-stages buffers
        if (kb < 3) {
            __builtin_amdgcn_s_barrier();
            __builtin_amdgcn_sched_barrier(0);
        }
    }

    // epilogue: C/D layout col=lane&15, row=(lane>>4)*4+reg
    const int ln = lane & 15;
    const int lq = (lane >> 4) * 4;
    float bv[4];
    #pragma unroll
    for (int j = 0; j < 4; ++j)
        bv[j] = bias[nj * C3 + nb * BN + wc + j * 16 + ln];
    #pragma unroll
    for (int i = 0; i < 4; ++i) {
        #pragma unroll
        for (int r = 0; r < 4; ++r) {
            int trow = mb * BM + wr + i * 16 + lq + r;   // local within chunk
            size_t base = ((size_t)trow * NJ + nj) * C3 + (size_t)nb * BN;
            #pragma unroll
            for (int j = 0; j < 4; ++j) {
                float val = acc[i][j][r] + bv[j];
                qkv[base + wc + j * 16 + ln] = f2h(val);
            }
        }
    }
}

// ---------------- attention + residual + LayerNorm ----------------
__global__ __launch_bounds__(256, 6)
void attn_ln(const unsigned short* __restrict__ qkv, const float* __restrict__ x,
             const float* __restrict__ gamma, const float* __restrict__ beta,
             float* __restrict__ out, int t0) {
    const int tloc = blockIdx.x;
    const int t = t0 + tloc;
    const int tid = threadIdx.x;
    const int wave = tid >> 6, lane = tid & 63;

    __shared__ __align__(16) unsigned short kv[NJ * 512];
    __shared__ float red[8];
    __shared__ float stats[2];
    float4* os4 = (float4*)kv;

    const uint4* tok = (const uint4*)(qkv + (size_t)tloc * (NJ * C3));

    #pragma unroll
    for (int j = 0; j < 6; ++j) {
        int idx = tid + j * 256;
        int m = idx >> 6, r = idx & 63;
        ((uint4*)kv)[(m << 6) + r] = tok[m * 96 + 32 + r];
    }

    const bool active = tid < NH * NJ;
    const int h = active ? (tid / NJ) : 0;
    const int n = active ? (tid - h * NJ) : 0;
    unsigned int qp[16];
    if (active) {
        const uint4* qsrc = tok + n * 96 + h * 4;
        #pragma unroll
        for (int jj = 0; jj < 4; ++jj) {
            uint4 w = qsrc[jj];
            qp[jj * 4 + 0] = w.x; qp[jj * 4 + 1] = w.y;
            qp[jj * 4 + 2] = w.z; qp[jj * 4 + 3] = w.w;
        }
    }
    __syncthreads();

    half2v o2[16];
    if (active) {
        const unsigned short* kbase = kv + h * FF;
        float s[NJ];
        float mx = -1e30f;
        #pragma unroll
        for (int m = 0; m < NJ; ++m) {
            const uint4* kp = (const uint4*)(kbase + m * 512);
            float a = 0.f;
            #pragma unroll
            for (int jj = 0; jj < 4; ++jj) {
                uint4 kw = kp[jj];
                a = dot2(kw.x, qp[jj * 4 + 0], a);
                a = dot2(kw.y, qp[jj * 4 + 1], a);
                a = dot2(kw.z, qp[jj * 4 + 2], a);
                a = dot2(kw.w, qp[jj * 4 + 3], a);
            }
            a *= 0.17677669529663687f;   // 1/sqrt(32)
            s[m] = a;
            mx = fmaxf(mx, a);
        }
        float sum = 0.f;
        #pragma unroll
        for (int m = 0; m < NJ; ++m) { s[m] = __expf(s[m] - mx); sum += s[m]; }
        float inv = 1.f / sum;
        #pragma unroll
        for (int k = 0; k < 16; ++k) o2[k] = half2v{(_Float16)0.f, (_Float16)0.f};
        const unsigned short* vbase = kv + 256 + h * FF;
        #pragma unroll
        for (int m = 0; m < NJ; ++m) {
            float wm = s[m] * inv;
            half2v wv = __builtin_bit_cast(half2v, __builtin_amdgcn_cvt_pkrtz(wm, wm));
            const uint4* vp = (const uint4*)(vbase + m * 512);
            #pragma unroll
            for (int jj = 0; jj < 4; ++jj) {
                uint4 vw = vp[jj];
                o2[jj * 4 + 0] += __builtin_bit_cast(half2v, vw.x) * wv;
                o2[jj * 4 + 1] += __builtin_bit_cast(half2v, vw.y) * wv;
                o2[jj * 4 + 2] += __builtin_bit_cast(half2v, vw.z) * wv;
                o2[jj * 4 + 3] += __builtin_bit_cast(half2v, vw.w) * wv;
            }
        }
    }
    __syncthreads();   // all K/V reads done; safe to overwrite kv as os
    if (active) {
        int base4 = n * 64 + h * 8;
        #pragma unroll
        for (int jj = 0; jj < 8; ++jj) {
            int wi = base4 + jj;
            int sw = wi ^ ((wi >> 6) & 7);
            os4[sw] = make_float4((float)o2[jj * 2][0], (float)o2[jj * 2][1],
                                  (float)o2[jj * 2 + 1][0], (float)o2[jj * 2 + 1][1]);
        }
    }
    __syncthreads();

    const float4* x4 = (const float4*)(x + (size_t)t * (NJ * DD));
    float4 yv[6];
    float sum = 0.f, sq = 0.f;
    #pragma unroll
    for (int j = 0; j < 6; ++j) {
        int ri = tid + j * 256;
        float4 a = x4[ri];
        float4 b = os4[ri ^ ((ri >> 6) & 7)];
        float4 y;
        y.x = a.x + b.x; y.y = a.y + b.y; y.z = a.z + b.z; y.w = a.w + b.w;
        yv[j] = y;
        sum += y.x + y.y + y.z + y.w;
        sq  += y.x * y.x + y.y * y.y + y.z * y.z + y.w * y.w;
    }
    #pragma unroll
    for (int off = 32; off > 0; off >>= 1) {
        sum += __shfl_down(sum, off);
        sq  += __shfl_down(sq, off);
    }
    if (lane == 0) { red[wave] = sum; red[4 + wave] = sq; }
    __syncthreads();
    if (tid == 0) {
        float s = red[0] + red[1] + red[2] + red[3];
        float q = red[4] + red[5] + red[6] + red[7];
        float mu = s * (1.f / 6144.f);
        float var = q * (1.f / 6144.f) - mu * mu;
        stats[0] = mu;
        stats[1] = rsqrtf(var + 1e-5f);
    }
    __syncthreads();
    const float mu = stats[0], rs = stats[1];
    const float4* g4 = (const float4*)gamma;
    const float4* b4 = (const float4*)beta;
    float4* out4 = (float4*)(out + (size_t)t * (NJ * DD));
    #pragma unroll
    for (int j = 0; j < 6; ++j) {
        float4 g = g4[tid + j * 256];
        float4 bb = b4[tid + j * 256];
        float4 y = yv[j];
        y.x = (y.x - mu) * rs * g.x + bb.x;
        y.y = (y.y - mu) * rs * g.y + bb.y;
        y.z = (y.z - mu) * rs * g.z + bb.z;
        y.w = (y.w - mu) * rs * g.w + bb.w;
        out4[tid + j * 256] = y;
    }
}

// ---------------- launch ----------------
extern "C" void kernel_launch(void* const* d_in, const int* in_sizes, int n_in,
                              void* d_out, int out_size, void* d_ws, size_t ws_size,
                              hipStream_t stream) {
    const float* x     = (const float*)d_in[0];
    const float* Wq    = (const float*)d_in[1];
    const float* bq    = (const float*)d_in[2];
    const float* Wk    = (const float*)d_in[3];
    const float* bk    = (const float*)d_in[4];
    const float* Wv    = (const float*)d_in[5];
    const float* bv    = (const float*)d_in[6];
    const float* gamma = (const float*)d_in[7];
    const float* beta  = (const float*)d_in[8];
    float* out = (float*)d_out;

    char* ws = (char*)d_ws;
    const size_t wbt_bytes  = (size_t)NJ * C3 * DD * 2;        // 9,437,184
    const size_t bias_bytes = (size_t)NJ * C3 * 4;             // 73,728
    unsigned short* wbt = (unsigned short*)ws;
    float* bias = (float*)(ws + wbt_bytes);
    unsigned short* qkv = (unsigned short*)(ws + wbt_bytes + bias_bytes);

    // chunk tokens so qkv scratch fits in remaining ws
    const size_t fixed = wbt_bytes + bias_bytes;
    size_t avail = (ws_size > fixed) ? ws_size - fixed : 0;
    int chunk = NT;
    while (chunk > BM && (size_t)chunk * NJ * C3 * 2 > avail) chunk >>= 1;

    pack_wb<<<dim3(280), dim3(256), 0, stream>>>(Wq, Wk, Wv, wbt, bq, bk, bv, bias);

    for (int t0 = 0; t0 < NT; t0 += chunk) {
        int mbs = chunk / BM;
        gemm_qkv<<<dim3(6 * mbs * NJ), dim3(256), 0, stream>>>(x, wbt, bias, qkv, t0, mbs);
        attn_ln<<<dim3(chunk), dim3(256), 0, stream>>>(qkv, x, gamma, beta, out, t0);
    }
}

// Round 9
// 575.491 us; speedup vs baseline: 1.0508x; 1.0508x over previous
//
#include <hip/hip_runtime.h>

#define NT 8192       // tokens
#define NJ 24         // joints
#define DD 256        // per-joint dim
#define NH 8          // heads
#define FF 32         // head dim
#define C3 768        // q(256) + k(256) + v(256)

typedef __attribute__((ext_vector_type(8))) _Float16 f16x8;
typedef __attribute__((ext_vector_type(2))) _Float16 half2v;
typedef __attribute__((ext_vector_type(4))) float f32x4;

__device__ __forceinline__ unsigned short f2h(float f) {
    union { _Float16 h; unsigned short u; } c;
    c.h = (_Float16)f;
    return c.u;
}

// fused dot2: a,b are packed f16 pairs (as uint), f32 accumulate
__device__ __forceinline__ float dot2(unsigned int a, unsigned int b, float c) {
#if __has_builtin(__builtin_amdgcn_fdot2)
    return __builtin_amdgcn_fdot2(__builtin_bit_cast(half2v, a),
                                  __builtin_bit_cast(half2v, b), c, false);
#else
    half2v ha = __builtin_bit_cast(half2v, a);
    half2v hb = __builtin_bit_cast(half2v, b);
    return c + (float)ha[0] * (float)hb[0] + (float)ha[1] * (float)hb[1];
#endif
}

// async global->LDS, 16B per lane. LDS dest = base + lane*16 (wave-uniform base).
__device__ __forceinline__ void gload16(const void* g, void* l) {
    __builtin_amdgcn_global_load_lds(
        (const __attribute__((address_space(1))) unsigned int*)g,
        (__attribute__((address_space(3))) unsigned int*)l, 16, 0, 0);
}

// ---------------- pack kernel (coalesced LDS-transpose) ----------------
__global__ __launch_bounds__(256)
void pack_wb(const float* __restrict__ Wq, const float* __restrict__ Wk,
             const float* __restrict__ Wv, unsigned short* __restrict__ wbt,
             const float* __restrict__ bq, const float* __restrict__ bk,
             const float* __restrict__ bv, float* __restrict__ bias) {
    const int b = blockIdx.x;
    const int tid = threadIdx.x;

    if (b < 208) {
        const float* src;
        int n0, nrep, crow0;
        if (b < 192) {
            int h = b / 24, n = b % 24;
            src = Wq + (size_t)(h * NJ + n) * (DD * FF);
            n0 = n; nrep = 1; crow0 = h * FF;
        } else if (b < 200) {
            int h = b - 192;
            src = Wk + (size_t)h * (DD * FF);
            n0 = 0; nrep = NJ; crow0 = 256 + h * FF;
        } else {
            int h = b - 200;
            src = Wv + (size_t)h * (DD * FF);
            n0 = 0; nrep = NJ; crow0 = 512 + h * FF;
        }
        __shared__ unsigned short T[32][264];   // +8 pad
        #pragma unroll
        for (int it = 0; it < 4; ++it) {
            int e = (it * 256 + tid) * 8;   // multiple of 8
            int d = e >> 5;
            int f = e & 31;
            float4 v0 = *(const float4*)(src + e);
            float4 v1 = *(const float4*)(src + e + 4);
            T[f + 0][d] = f2h(v0.x); T[f + 1][d] = f2h(v0.y);
            T[f + 2][d] = f2h(v0.z); T[f + 3][d] = f2h(v0.w);
            T[f + 4][d] = f2h(v1.x); T[f + 5][d] = f2h(v1.y);
            T[f + 6][d] = f2h(v1.z); T[f + 7][d] = f2h(v1.w);
        }
        __syncthreads();
        for (int rep = 0; rep < nrep; ++rep) {
            int n = n0 + rep;
            unsigned short* dst = wbt + ((size_t)n * C3 + crow0) * DD;
            #pragma unroll
            for (int it = 0; it < 4; ++it) {
                int q = it * 256 + tid;       // 0..1023
                int r = q >> 5;               // row 0..31
                int c8 = (q & 31) * 8;        // 8 shorts
                *(int4*)(dst + r * DD + c8) = *(const int4*)&T[r][c8];
            }
        }
    } else {
        int idx = (b - 208) * 256 + tid;
        int cb = idx % C3;
        int nb2 = idx / C3;
        float bvv;
        if (cb < 256) {
            int h = cb >> 5, f = cb & 31;
            bvv = bq[((h * NJ + nb2) * FF) + f];
        } else if (cb < 512) {
            int cc = cb - 256; int h = cc >> 5, f = cc & 31;
            bvv = bk[h * FF + f];
        } else {
            int cc = cb - 512; int h = cc >> 5, f = cc & 31;
            bvv = bv[h * FF + f];
        }
        bias[idx] = bvv;
    }
}

// ---------------- QKV projection GEMM ----------------
// 2-phase pipeline, B-only LDS double-buffer (As 16K + Bs 32K = 48KB -> 3/CU).
// A-path is reg-level double-buffered (pa prefetch). Wait chain:
//   phase1 cvt reads pa(kb) -> compiler vmcnt(0) also drains B(kb) (older).
//   B(kb+1)+pa(kb+1) issued AFTER phase1 -> fly across lgkm0+barrier+MFMA.
// Raw barriers (no vmcnt drain) keep those loads in flight (T4).
#define BM 128
#define BN 128

__global__ __launch_bounds__(256, 3)
void gemm_qkv(const float* __restrict__ x, const unsigned short* __restrict__ wbt,
              const float* __restrict__ bias, unsigned short* __restrict__ qkv,
              int t0, int mbs) {
    // XCD-chunked bijective swizzle: nwg = 144*mbs, always % 8 == 0.
    const int nwg = gridDim.x;
    const int cpx = nwg >> 3;
    const int bid = blockIdx.x;
    const int swz = (bid & 7) * cpx + (bid >> 3);
    const int nb = swz % 6;          // col block (0..5) — fastest: shares A-tile
    const int rest = swz / 6;
    const int mb = rest % mbs;       // token block
    const int nj = rest / mbs;       // joint

    const int tid = threadIdx.x;
    const int wave = tid >> 6, lane = tid & 63;

    __shared__ unsigned short As[BM * 64];      // 16 KB (single, reg-dbuf'd A)
    __shared__ unsigned short Bs[2][BN * 64];   // 2 x 16 KB

    f32x4 acc[4][4];
    #pragma unroll
    for (int i = 0; i < 4; ++i)
        #pragma unroll
        for (int j = 0; j < 4; ++j)
            #pragma unroll
            for (int r = 0; r < 4; ++r) acc[i][j][r] = 0.f;

    const int trow0 = t0 + mb * BM;
    const float* srcA = x + (size_t)trow0 * (NJ * DD) + nj * DD;
    const char* srcB = (const char*)(wbt + ((size_t)nj * C3 + (size_t)nb * BN) * DD);

    const int rg = lane >> 3;            // row within 8-row group (0..7)
    const int sc = (lane & 7) ^ rg;      // pre-swizzled source 16B-column (B staging)

    const int wr = (wave >> 1) * 64;
    const int wc = (wave & 1) * 64;
    const int lr = lane & 15;
    const int g  = lane >> 4;            // 0..3

    const float* aptr[4];
    #pragma unroll
    for (int it = 0; it < 4; ++it) {
        int q = it * 256 + tid;          // 0..1023
        int row = q >> 3;
        int c16 = q & 7;
        aptr[it] = srcA + (size_t)row * (NJ * DD) + c16 * 8;
    }

    // prologue: B(0) -> Bs[0] issued FIRST, then A(0) -> pa regs
    #pragma unroll
    for (int i = 0; i < 4; ++i) {
        int row0 = wave * 32 + i * 8;
        gload16(srcB + (size_t)(row0 + rg) * (DD * 2) + sc * 16,
                (char*)Bs[0] + row0 * 128);
    }
    float4 pa[4][2];
    #pragma unroll
    for (int it = 0; it < 4; ++it) {
        pa[it][0] = *(const float4*)(aptr[it]);
        pa[it][1] = *(const float4*)(aptr[it] + 4);
    }

    #pragma unroll
    for (int kb = 0; kb < 4; ++kb) {
        const int cur = kb & 1;
        // 1. cvt + swizzled ds_write A(kb). Compiler vmcnt wait on pa(kb)
        //    drains B(kb) too (issued earlier).
        #pragma unroll
        for (int it = 0; it < 4; ++it) {
            int q = it * 256 + tid;
            int row = q >> 3;
            int c16 = q & 7;
            float4 v0 = pa[it][0];
            float4 v1 = pa[it][1];
            f16x8 hv;
            hv[0] = (_Float16)v0.x; hv[1] = (_Float16)v0.y;
            hv[2] = (_Float16)v0.z; hv[3] = (_Float16)v0.w;
            hv[4] = (_Float16)v1.x; hv[5] = (_Float16)v1.y;
            hv[6] = (_Float16)v1.z; hv[7] = (_Float16)v1.w;
            int c16s = c16 ^ (row & 7);
            *(f16x8*)((char*)As + row * 128 + c16s * 16) = hv;
        }
        // 2. stage next tile into Bs[cur^1] (sealed by barrier#5 of kb-1) + pa regs.
        if (kb < 3) {
            #pragma unroll
            for (int i = 0; i < 4; ++i) {
                int row0 = wave * 32 + i * 8;
                gload16(srcB + (size_t)(row0 + rg) * (DD * 2) + (kb + 1) * 128 + sc * 16,
                        (char*)Bs[cur ^ 1] + row0 * 128);
            }
            #pragma unroll
            for (int it = 0; it < 4; ++it) {
                const float* p = aptr[it] + (kb + 1) * 64;
                pa[it][0] = *(const float4*)p;
                pa[it][1] = *(const float4*)(p + 4);
            }
        }
        // 3. LDS-write fence + raw barrier (no vmcnt drain: staged loads stay in flight)
        asm volatile("s_waitcnt lgkmcnt(0)" ::: "memory");
        __builtin_amdgcn_sched_barrier(0);
        __builtin_amdgcn_s_barrier();
        // 4. MFMA on As / Bs[cur]
        #pragma unroll
        for (int kk = 0; kk < 2; ++kk) {
            f16x8 a[4], b[4];
            #pragma unroll
            for (int i = 0; i < 4; ++i) {
                int row = wr + i * 16 + lr;
                int c16 = (kk * 4 + g) ^ (row & 7);
                a[i] = *(const f16x8*)((const char*)As + row * 128 + c16 * 16);
            }
            #pragma unroll
            for (int j = 0; j < 4; ++j) {
                int row = wc + j * 16 + lr;
                int c16 = (kk * 4 + g) ^ (row & 7);
                b[j] = *(const f16x8*)((const char*)Bs[cur] + row * 128 + c16 * 16);
            }
            #pragma unroll
            for (int i = 0; i < 4; ++i)
                #pragma unroll
                for (int j = 0; j < 4; ++j)
                    acc[i][j] = __builtin_amdgcn_mfma_f32_16x16x32_f16(a[i], b[j], acc[i][j], 0, 0, 0);
        }
        // 5. raw barrier: MFMA(kb) LDS reads done before next iter overwrites As/Bs
        if (kb < 3) {
            __builtin_amdgcn_s_barrier();
            __builtin_amdgcn_sched_barrier(0);
        }
    }

    // epilogue: C/D layout col=lane&15, row=(lane>>4)*4+reg
    const int ln = lane & 15;
    const int lq = (lane >> 4) * 4;
    float bv[4];
    #pragma unroll
    for (int j = 0; j < 4; ++j)
        bv[j] = bias[nj * C3 + nb * BN + wc + j * 16 + ln];
    #pragma unroll
    for (int i = 0; i < 4; ++i) {
        #pragma unroll
        for (int r = 0; r < 4; ++r) {
            int trow = mb * BM + wr + i * 16 + lq + r;   // local within chunk
            size_t base = ((size_t)trow * NJ + nj) * C3 + (size_t)nb * BN;
            #pragma unroll
            for (int j = 0; j < 4; ++j) {
                float val = acc[i][j][r] + bv[j];
                qkv[base + wc + j * 16 + ln] = f2h(val);
            }
        }
    }
}

// ---------------- attention + residual + LayerNorm ----------------
__global__ __launch_bounds__(256, 6)
void attn_ln(const unsigned short* __restrict__ qkv, const float* __restrict__ x,
             const float* __restrict__ gamma, const float* __restrict__ beta,
             float* __restrict__ out, int t0) {
    const int tloc = blockIdx.x;
    const int t = t0 + tloc;
    const int tid = threadIdx.x;
    const int wave = tid >> 6, lane = tid & 63;

    __shared__ __align__(16) unsigned short kv[NJ * 512];
    __shared__ float red[8];
    __shared__ float stats[2];
    float4* os4 = (float4*)kv;

    const uint4* tok = (const uint4*)(qkv + (size_t)tloc * (NJ * C3));

    #pragma unroll
    for (int j = 0; j < 6; ++j) {
        int idx = tid + j * 256;
        int m = idx >> 6, r = idx & 63;
        ((uint4*)kv)[(m << 6) + r] = tok[m * 96 + 32 + r];
    }

    const bool active = tid < NH * NJ;
    const int h = active ? (tid / NJ) : 0;
    const int n = active ? (tid - h * NJ) : 0;
    unsigned int qp[16];
    if (active) {
        const uint4* qsrc = tok + n * 96 + h * 4;
        #pragma unroll
        for (int jj = 0; jj < 4; ++jj) {
            uint4 w = qsrc[jj];
            qp[jj * 4 + 0] = w.x; qp[jj * 4 + 1] = w.y;
            qp[jj * 4 + 2] = w.z; qp[jj * 4 + 3] = w.w;
        }
    }
    __syncthreads();

    half2v o2[16];
    if (active) {
        const unsigned short* kbase = kv + h * FF;
        float s[NJ];
        float mx = -1e30f;
        #pragma unroll
        for (int m = 0; m < NJ; ++m) {
            const uint4* kp = (const uint4*)(kbase + m * 512);
            float a = 0.f;
            #pragma unroll
            for (int jj = 0; jj < 4; ++jj) {
                uint4 kw = kp[jj];
                a = dot2(kw.x, qp[jj * 4 + 0], a);
                a = dot2(kw.y, qp[jj * 4 + 1], a);
                a = dot2(kw.z, qp[jj * 4 + 2], a);
                a = dot2(kw.w, qp[jj * 4 + 3], a);
            }
            a *= 0.17677669529663687f;   // 1/sqrt(32)
            s[m] = a;
            mx = fmaxf(mx, a);
        }
        float sum = 0.f;
        #pragma unroll
        for (int m = 0; m < NJ; ++m) { s[m] = __expf(s[m] - mx); sum += s[m]; }
        float inv = 1.f / sum;
        #pragma unroll
        for (int k = 0; k < 16; ++k) o2[k] = half2v{(_Float16)0.f, (_Float16)0.f};
        const unsigned short* vbase = kv + 256 + h * FF;
        #pragma unroll
        for (int m = 0; m < NJ; ++m) {
            float wm = s[m] * inv;
            half2v wv = __builtin_bit_cast(half2v, __builtin_amdgcn_cvt_pkrtz(wm, wm));
            const uint4* vp = (const uint4*)(vbase + m * 512);
            #pragma unroll
            for (int jj = 0; jj < 4; ++jj) {
                uint4 vw = vp[jj];
                o2[jj * 4 + 0] += __builtin_bit_cast(half2v, vw.x) * wv;
                o2[jj * 4 + 1] += __builtin_bit_cast(half2v, vw.y) * wv;
                o2[jj * 4 + 2] += __builtin_bit_cast(half2v, vw.z) * wv;
                o2[jj * 4 + 3] += __builtin_bit_cast(half2v, vw.w) * wv;
            }
        }
    }
    __syncthreads();   // all K/V reads done; safe to overwrite kv as os
    if (active) {
        int base4 = n * 64 + h * 8;
        #pragma unroll
        for (int jj = 0; jj < 8; ++jj) {
            int wi = base4 + jj;
            int sw = wi ^ ((wi >> 6) & 7);
            os4[sw] = make_float4((float)o2[jj * 2][0], (float)o2[jj * 2][1],
                                  (float)o2[jj * 2 + 1][0], (float)o2[jj * 2 + 1][1]);
        }
    }
    __syncthreads();

    const float4* x4 = (const float4*)(x + (size_t)t * (NJ * DD));
    float4 yv[6];
    float sum = 0.f, sq = 0.f;
    #pragma unroll
    for (int j = 0; j < 6; ++j) {
        int ri = tid + j * 256;
        float4 a = x4[ri];
        float4 b = os4[ri ^ ((ri >> 6) & 7)];
        float4 y;
        y.x = a.x + b.x; y.y = a.y + b.y; y.z = a.z + b.z; y.w = a.w + b.w;
        yv[j] = y;
        sum += y.x + y.y + y.z + y.w;
        sq  += y.x * y.x + y.y * y.y + y.z * y.z + y.w * y.w;
    }
    #pragma unroll
    for (int off = 32; off > 0; off >>= 1) {
        sum += __shfl_down(sum, off);
        sq  += __shfl_down(sq, off);
    }
    if (lane == 0) { red[wave] = sum; red[4 + wave] = sq; }
    __syncthreads();
    if (tid == 0) {
        float s = red[0] + red[1] + red[2] + red[3];
        float q = red[4] + red[5] + red[6] + red[7];
        float mu = s * (1.f / 6144.f);
        float var = q * (1.f / 6144.f) - mu * mu;
        stats[0] = mu;
        stats[1] = rsqrtf(var + 1e-5f);
    }
    __syncthreads();
    const float mu = stats[0], rs = stats[1];
    const float4* g4 = (const float4*)gamma;
    const float4* b4 = (const float4*)beta;
    float4* out4 = (float4*)(out + (size_t)t * (NJ * DD));
    #pragma unroll
    for (int j = 0; j < 6; ++j) {
        float4 g = g4[tid + j * 256];
        float4 bb = b4[tid + j * 256];
        float4 y = yv[j];
        y.x = (y.x - mu) * rs * g.x + bb.x;
        y.y = (y.y - mu) * rs * g.y + bb.y;
        y.z = (y.z - mu) * rs * g.z + bb.z;
        y.w = (y.w - mu) * rs * g.w + bb.w;
        out4[tid + j * 256] = y;
    }
}

// ---------------- launch ----------------
extern "C" void kernel_launch(void* const* d_in, const int* in_sizes, int n_in,
                              void* d_out, int out_size, void* d_ws, size_t ws_size,
                              hipStream_t stream) {
    const float* x     = (const float*)d_in[0];
    const float* Wq    = (const float*)d_in[1];
    const float* bq    = (const float*)d_in[2];
    const float* Wk    = (const float*)d_in[3];
    const float* bk    = (const float*)d_in[4];
    const float* Wv    = (const float*)d_in[5];
    const float* bv    = (const float*)d_in[6];
    const float* gamma = (const float*)d_in[7];
    const float* beta  = (const float*)d_in[8];
    float* out = (float*)d_out;

    char* ws = (char*)d_ws;
    const size_t wbt_bytes  = (size_t)NJ * C3 * DD * 2;        // 9,437,184
    const size_t bias_bytes = (size_t)NJ * C3 * 4;             // 73,728
    unsigned short* wbt = (unsigned short*)ws;
    float* bias = (float*)(ws + wbt_bytes);
    unsigned short* qkv = (unsigned short*)(ws + wbt_bytes + bias_bytes);

    // chunk = 2048 tokens: qkv scratch (75 MB) + x-chunk (50 MB) + out-chunk
    // (50 MB) stay L3-resident -> gemm's qkv writes absorbed, attn's reads hit L3.
    const size_t fixed = wbt_bytes + bias_bytes;
    size_t avail = (ws_size > fixed) ? ws_size - fixed : 0;
    int chunk = 2048;
    while (chunk > BM && (size_t)chunk * NJ * C3 * 2 > avail) chunk >>= 1;

    pack_wb<<<dim3(280), dim3(256), 0, stream>>>(Wq, Wk, Wv, wbt, bq, bk, bv, bias);

    for (int t0 = 0; t0 < NT; t0 += chunk) {
        int mbs = chunk / BM;
        gemm_qkv<<<dim3(6 * mbs * NJ), dim3(256), 0, stream>>>(x, wbt, bias, qkv, t0, mbs);
        attn_ln<<<dim3(chunk), dim3(256), 0, stream>>>(qkv, x, gamma, beta, out, t0);
    }
}